// Round 1
// baseline (422.391 us; speedup 1.0000x reference)
//
#include <hip/hip_runtime.h>

#define EPS 1e-5f

typedef __bf16 bf16x8 __attribute__((ext_vector_type(8)));
typedef float  f32x4  __attribute__((ext_vector_type(4)));

__device__ __forceinline__ unsigned short f2bf(float f) {
  unsigned int u = __float_as_uint(f);
  unsigned int r = (u + 0x7fffu + ((u >> 16) & 1u)) >> 16;
  return (unsigned short)r;
}
__device__ __forceinline__ float silu(float y) { return y / (1.f + __expf(-y)); }

// ---------------- feat = SiLU(BN(conv1x1(x, w1))) -> [B,400,128] (p-major, c contiguous)
__global__ void feat_kernel(const float* __restrict__ x, const float* __restrict__ w1,
                            const float* __restrict__ g1, const float* __restrict__ b1,
                            const float* __restrict__ m1, const float* __restrict__ v1,
                            float* __restrict__ feat) {
  int blk = blockIdx.x; int b = blk / 400, p = blk % 400;
  int tid = threadIdx.x;
  __shared__ float xv[128];
  xv[tid] = x[(b * 128 + tid) * 400 + p];
  __syncthreads();
  const float* wrow = w1 + tid * 128;
  float s = 0.f;
#pragma unroll 8
  for (int ci = 0; ci < 128; ++ci) s += wrow[ci] * xv[ci];
  float sc = g1[tid] * rsqrtf(v1[tid] + EPS);
  float y = s * sc + (b1[tid] - m1[tid] * sc);
  feat[(b * 400 + p) * 128 + tid] = silu(y);
}

// ---------------- pack wr2 [128,128,3,3] into MFMA A-fragment layout, bf16.
// frag f = tap*32 + ks*8 + mt ; lane element j: A[o = mt*16 + (lane&15)][c = ks*32 + (lane>>4)*8 + j]
__global__ void pack_w2(const float* __restrict__ wr2, unsigned short* __restrict__ Apack) {
  int f = blockIdx.x;
  int lane = threadIdx.x;
  int tap = f >> 5, ks = (f >> 3) & 3, mt = f & 7;
  int o  = mt * 16 + (lane & 15);
  int cb = ks * 32 + (lane >> 4) * 8;
  unsigned short* dst = Apack + ((size_t)f * 64 + lane) * 8;
#pragma unroll
  for (int j = 0; j < 8; ++j)
    dst[j] = f2bf(wr2[(o * 128 + (cb + j)) * 9 + tap]);
}

// ---------------- per-image fused relational stack: conv1(lowrank)+BN+SiLU -> conv3x3(MFMA)+BN+SiLU
//                  -> conv1x1->score -> BN+SiLU -> att row = scores @ feat
__global__ __launch_bounds__(512, 2) void rel_kernel(
    const float* __restrict__ feat, const float* __restrict__ wr1,
    const float* __restrict__ gr1, const float* __restrict__ br1,
    const float* __restrict__ mr1, const float* __restrict__ vr1,
    const unsigned short* __restrict__ Apack,
    const float* __restrict__ gr2, const float* __restrict__ br2,
    const float* __restrict__ mr2, const float* __restrict__ vr2,
    const float* __restrict__ wr3,
    const float* __restrict__ gr3, const float* __restrict__ br3,
    const float* __restrict__ mr3, const float* __restrict__ vr3,
    float* __restrict__ att) {

  __shared__ __align__(16) unsigned short r1s[400 * 136];   // 108800 B  r1 bf16, [pixel][chan], stride 136
  __shared__ __align__(16) unsigned short wtap[16384];      //  32768 B  one tap of packed weights
  __shared__ float f0s[400], f1s[400], scoreS[400];
  __shared__ float AvecS[128], wB0s[128], wB1s[128];
  __shared__ float sc1[128], sh1[128], sc2[128], sh2[128], w3c[128];
  __shared__ float fA[256];
  __shared__ int   selS[256];
  __shared__ float attT[128];
  __shared__ __align__(16) unsigned short zslot[8];

  int tid = threadIdx.x;
  int n0 = blockIdx.x;
  int b = n0 / 400, q = n0 % 400;
  int c_lo = (q * 256) / 400;

  // ---- phase 0: constants & classification
  if (tid < 128) {
    float s1 = gr1[tid] * rsqrtf(vr1[tid] + EPS); sc1[tid] = s1; sh1[tid] = br1[tid] - mr1[tid] * s1;
    float s2 = gr2[tid] * rsqrtf(vr2[tid] + EPS); sc2[tid] = s2; sh2[tid] = br2[tid] - mr2[tid] * s2;
    w3c[tid] = wr3[tid];
    attT[tid] = 0.f;
  }
  if (tid < 256) {
    int u = q * 256 + tid; int c = u / 400; int i = u - c * 400;
    if (c < 128) { fA[tid] = feat[(b * 400 + i) * 128 + c]; selS[tid] = -1; }
    else         { fA[tid] = 0.f;                            selS[tid] = c - c_lo; }  // 0 or 1
  }
  if (tid < 8) zslot[tid] = 0;
  for (int p = tid; p < 400; p += 512) {
    int c0 = c_lo, c1 = c_lo + 1;
    f0s[p] = (c0 >= 128 && c0 < 256) ? feat[(b * 400 + p) * 128 + (c0 - 128)] : 0.f;
    f1s[p] = (c1 >= 128 && c1 < 256) ? feat[(b * 400 + p) * 128 + (c1 - 128)] : 0.f;
    scoreS[p] = 0.f;
  }
  __syncthreads();

  // ---- conv1 low-rank coefficients:  r1_pre[o,p] = A[o] + wB0[o]*f0[p] + wB1[o]*f1[p]
  if (tid < 128) {
    float a = 0.f, w0 = 0.f, w1v = 0.f;
    const float* wr = wr1 + tid * 256;
    for (int cp = 0; cp < 256; ++cp) {
      float w = wr[cp]; int s = selS[cp];
      if (s < 0)      a   += w * fA[cp];
      else if (s == 0) w0 += w;
      else             w1v += w;
    }
    AvecS[tid] = a; wB0s[tid] = w0; wB1s[tid] = w1v;
  }
  __syncthreads();

  // ---- phase 1: r1 = SiLU(BN(r1_pre)) -> LDS bf16
  for (int idx = tid; idx < 51200; idx += 512) {
    int p = idx >> 7, o = idx & 127;
    float y = AvecS[o] + wB0s[o] * f0s[p] + wB1s[o] * f1s[p];
    y = y * sc1[o] + sh1[o];
    r1s[p * 136 + o] = f2bf(silu(y));
  }
  // (first tap iteration's barrier covers these writes)

  // ---- phase 2: conv2 as 9 shifted GEMMs with MFMA 16x16x32 bf16
  int lane = tid & 63, wid = tid >> 6;
  int wm = wid & 1, wn = wid >> 1;          // 2 m-halves x 4 n-groups
  int ntbase = wn * 7, ntcnt = (wn == 3) ? 4 : 7;
  int n16 = lane & 15, quad = lane >> 4;

  f32x4 acc[4][7];
#pragma unroll
  for (int mt = 0; mt < 4; ++mt)
#pragma unroll
    for (int t = 0; t < 7; ++t) acc[mt][t] = f32x4{0.f, 0.f, 0.f, 0.f};

  for (int tap = 0; tap < 9; ++tap) {
    __syncthreads();                         // previous tap's wtap reads done / phase-1 writes done
    {
      const uint4* src = (const uint4*)(Apack + (size_t)tap * 16384);
      uint4* dst = (uint4*)wtap;
      for (int r = tid; r < 2048; r += 512) dst[r] = src[r];
    }
    __syncthreads();
    int dy = tap / 3 - 1, dx = tap % 3 - 1;
    for (int ks = 0; ks < 4; ++ks) {
      bf16x8 afr[4];
#pragma unroll
      for (int mt = 0; mt < 4; ++mt)
        afr[mt] = *(const bf16x8*)&wtap[((ks * 8 + wm * 4 + mt) * 64 + lane) * 8];
#pragma unroll
      for (int t = 0; t < 7; ++t) {
        if (t < ntcnt) {                      // wave-uniform predicate
          int p = (ntbase + t) * 16 + n16;
          int h = p / 20, w = p - h * 20;
          int hh = h + dy, ww = w + dx;
          bool valid = (hh >= 0) & (hh < 20) & (ww >= 0) & (ww < 20);
          const unsigned short* ba = valid ? &r1s[(hh * 20 + ww) * 136 + ks * 32 + quad * 8] : zslot;
          bf16x8 bfr = *(const bf16x8*)ba;
          acc[0][t] = __builtin_amdgcn_mfma_f32_16x16x32_bf16(afr[0], bfr, acc[0][t], 0, 0, 0);
          acc[1][t] = __builtin_amdgcn_mfma_f32_16x16x32_bf16(afr[1], bfr, acc[1][t], 0, 0, 0);
          acc[2][t] = __builtin_amdgcn_mfma_f32_16x16x32_bf16(afr[2], bfr, acc[2][t], 0, 0, 0);
          acc[3][t] = __builtin_amdgcn_mfma_f32_16x16x32_bf16(afr[3], bfr, acc[3][t], 0, 0, 0);
        }
      }
    }
  }

  // ---- epilogue: BN2+SiLU, conv3 (dot with w3c), reduce to scoreS[p]
#pragma unroll
  for (int t = 0; t < 7; ++t) {
    if (t < ntcnt) {
      float ps = 0.f;
#pragma unroll
      for (int mt = 0; mt < 4; ++mt) {
#pragma unroll
        for (int r = 0; r < 4; ++r) {
          int o = wm * 64 + mt * 16 + quad * 4 + r;
          float y = acc[mt][t][r] * sc2[o] + sh2[o];
          ps += silu(y) * w3c[o];
        }
      }
      ps += __shfl_xor(ps, 16);
      ps += __shfl_xor(ps, 32);
      if (quad == 0) atomicAdd(&scoreS[(ntbase + t) * 16 + n16], ps);
    }
  }
  __syncthreads();

  // ---- BN3 + SiLU on scores
  float s3 = gr3[0] * rsqrtf(vr3[0] + EPS);
  float sh3v = br3[0] - mr3[0] * s3;
  for (int p = tid; p < 400; p += 512)
    scoreS[p] = silu(scoreS[p] * s3 + sh3v);
  __syncthreads();

  // ---- att row: att[b,q,c] = sum_j score[j] * feat[b,j,c]
  {
    int c = tid & 127, part = tid >> 7;   // 4 partial sums per c
    float s = 0.f;
    int j0 = part * 100;
    for (int j = j0; j < j0 + 100; ++j)
      s += scoreS[j] * feat[(b * 400 + j) * 128 + c];
    atomicAdd(&attT[c], s);
  }
  __syncthreads();
  if (tid < 128)
    att[((size_t)(b * 400 + q)) * 128 + tid] = attT[tid];
}

// ---------------- out = SiLU(BN(conv1x1(att, w2))) + x
__global__ void out_kernel(const float* __restrict__ att, const float* __restrict__ x,
                           const float* __restrict__ w2,
                           const float* __restrict__ g2, const float* __restrict__ b2,
                           const float* __restrict__ m2, const float* __restrict__ v2,
                           float* __restrict__ out) {
  int blk = blockIdx.x; int b = blk / 400, p = blk % 400;
  int tid = threadIdx.x;
  __shared__ float av[128];
  av[tid] = att[(size_t)(b * 400 + p) * 128 + tid];
  __syncthreads();
  const float* wrow = w2 + tid * 128;
  float s = 0.f;
#pragma unroll 8
  for (int ci = 0; ci < 128; ++ci) s += wrow[ci] * av[ci];
  float sc = g2[tid] * rsqrtf(v2[tid] + EPS);
  float y = s * sc + (b2[tid] - m2[tid] * sc);
  int xi = (b * 128 + tid) * 400 + p;
  out[xi] = silu(y) + x[xi];
}

extern "C" void kernel_launch(void* const* d_in, const int* in_sizes, int n_in,
                              void* d_out, int out_size, void* d_ws, size_t ws_size,
                              hipStream_t stream) {
  const float* x   = (const float*)d_in[0];
  const float* w1  = (const float*)d_in[1];
  const float* g1  = (const float*)d_in[2];
  const float* b1  = (const float*)d_in[3];
  const float* m1  = (const float*)d_in[4];
  const float* v1  = (const float*)d_in[5];
  const float* w2  = (const float*)d_in[6];
  const float* g2  = (const float*)d_in[7];
  const float* b2  = (const float*)d_in[8];
  const float* m2  = (const float*)d_in[9];
  const float* v2  = (const float*)d_in[10];
  const float* wr1 = (const float*)d_in[11];
  const float* gr1 = (const float*)d_in[12];
  const float* br1 = (const float*)d_in[13];
  const float* mr1 = (const float*)d_in[14];
  const float* vr1 = (const float*)d_in[15];
  const float* wr2 = (const float*)d_in[16];
  const float* gr2 = (const float*)d_in[17];
  const float* br2 = (const float*)d_in[18];
  const float* mr2 = (const float*)d_in[19];
  const float* vr2 = (const float*)d_in[20];
  const float* wr3 = (const float*)d_in[21];
  const float* gr3 = (const float*)d_in[22];
  const float* br3 = (const float*)d_in[23];
  const float* mr3 = (const float*)d_in[24];
  const float* vr3 = (const float*)d_in[25];
  float* out = (float*)d_out;

  char* ws = (char*)d_ws;
  float* feat = (float*)ws;                                // 409600 B
  float* attb = (float*)(ws + 409600);                     // 409600 B
  unsigned short* Apack = (unsigned short*)(ws + 819200);  // 294912 B

  feat_kernel<<<800, 128, 0, stream>>>(x, w1, g1, b1, m1, v1, feat);
  pack_w2<<<288, 64, 0, stream>>>(wr2, Apack);
  rel_kernel<<<800, 512, 0, stream>>>(feat, wr1, gr1, br1, mr1, vr1, Apack,
                                      gr2, br2, mr2, vr2, wr3, gr3, br3, mr3, vr3, attb);
  out_kernel<<<800, 128, 0, stream>>>(attb, x, w2, g2, b2, m2, v2, out);
}

// Round 2
// 400.550 us; speedup vs baseline: 1.0545x; 1.0545x over previous
//
#include <hip/hip_runtime.h>

#define EPS 1e-5f

typedef __bf16 bf16x8 __attribute__((ext_vector_type(8)));
typedef float  f32x4  __attribute__((ext_vector_type(4)));

__device__ __forceinline__ unsigned short f2bf(float f) {
  unsigned int u = __float_as_uint(f);
  unsigned int r = (u + 0x7fffu + ((u >> 16) & 1u)) >> 16;
  return (unsigned short)r;
}
__device__ __forceinline__ float silu(float y) { return y / (1.f + __expf(-y)); }

__device__ __forceinline__ void stage16(const void* g, void* l) {
  __builtin_amdgcn_global_load_lds((const __attribute__((address_space(1))) void*)g,
                                   (__attribute__((address_space(3))) void*)l, 16, 0, 0);
}

// ---------------- prep: feat (blocks 0..799) + weight pack (blocks 800..943)
// feat = SiLU(BN(conv1x1(x, w1))) -> [B,400,128] (p-major, c contiguous)
// pack wr2 [128,128,3,3] -> MFMA A-frag layout: frag f = tap*32 + ks*8 + mt8;
//   lane elem j: A[o = mt8*16 + (lane&15)][c = ks*32 + (lane>>4)*8 + j]
__global__ void prep_kernel(const float* __restrict__ x, const float* __restrict__ w1,
                            const float* __restrict__ g1, const float* __restrict__ b1,
                            const float* __restrict__ m1, const float* __restrict__ v1,
                            const float* __restrict__ wr2,
                            float* __restrict__ feat, unsigned short* __restrict__ Apack) {
  int blk = blockIdx.x;
  int tid = threadIdx.x;
  if (blk < 800) {
    int b = blk / 400, p = blk % 400;
    __shared__ float xv[128];
    xv[tid] = x[(b * 128 + tid) * 400 + p];
    __syncthreads();
    const float* wrow = w1 + tid * 128;
    float s = 0.f;
#pragma unroll 8
    for (int ci = 0; ci < 128; ++ci) s += wrow[ci] * xv[ci];
    float sc = g1[tid] * rsqrtf(v1[tid] + EPS);
    float y = s * sc + (b1[tid] - m1[tid] * sc);
    feat[(b * 400 + p) * 128 + tid] = silu(y);
  } else {
    int f = (blk - 800) * 2 + (tid >> 6);
    int lane = tid & 63;
    int tap = f >> 5, ks = (f >> 3) & 3, mt8 = f & 7;
    int o  = mt8 * 16 + (lane & 15);
    int cb = ks * 32 + (lane >> 4) * 8;
    unsigned short* dst = Apack + ((size_t)f * 64 + lane) * 8;
#pragma unroll
    for (int j = 0; j < 8; ++j)
      dst[j] = f2bf(wr2[(o * 128 + (cb + j)) * 9 + tap]);
  }
}

// ---------------- per-image fused relational stack
__global__ __launch_bounds__(512, 2) void rel_kernel(
    const float* __restrict__ feat, const float* __restrict__ wr1,
    const float* __restrict__ gr1, const float* __restrict__ br1,
    const float* __restrict__ mr1, const float* __restrict__ vr1,
    const unsigned short* __restrict__ Apack,
    const float* __restrict__ gr2, const float* __restrict__ br2,
    const float* __restrict__ mr2, const float* __restrict__ vr2,
    const float* __restrict__ wr3,
    const float* __restrict__ gr3, const float* __restrict__ br3,
    const float* __restrict__ mr3, const float* __restrict__ vr3,
    float* __restrict__ att) {

  // r1 bf16 in fragment-major planes: plane = ks*4+quad (16 planes), 401 pixel-slots
  // of 16 B each (slot 400 = zeros, used for out-of-image taps).
  __shared__ __align__(16) unsigned short r1f[16 * 401 * 8];   // 102656 B
  __shared__ __align__(16) unsigned short wbuf[2 * 8192];      //  32768 B (2 x 16KB chunks)
  __shared__ float f0s[400], f1s[400], scoreS[400];
  __shared__ float AvecS[128], wB0s[128], wB1s[128];
  __shared__ float sc1[128], sh1[128], sc2[128], sh2[128], w3c[128];
  __shared__ float fA[256];
  __shared__ int   selS[256];
  __shared__ float attT[128];

  int tid = threadIdx.x;
  int lane = tid & 63, wid = tid >> 6;
  int n0 = blockIdx.x;
  int b = n0 / 400, q = n0 % 400;
  int c_lo = (q * 256) / 400;

  // ---- phase 0: constants & classification
  if (tid < 128) {
    float s1 = gr1[tid] * rsqrtf(vr1[tid] + EPS); sc1[tid] = s1; sh1[tid] = br1[tid] - mr1[tid] * s1;
    float s2 = gr2[tid] * rsqrtf(vr2[tid] + EPS); sc2[tid] = s2; sh2[tid] = br2[tid] - mr2[tid] * s2;
    w3c[tid] = wr3[tid];
    attT[tid] = 0.f; AvecS[tid] = 0.f; wB0s[tid] = 0.f; wB1s[tid] = 0.f;
  }
  if (tid < 256) {
    int u = q * 256 + tid; int c = u / 400; int i = u - c * 400;
    if (c < 128) { fA[tid] = feat[(b * 400 + i) * 128 + c]; selS[tid] = -1; }
    else         { fA[tid] = 0.f;                            selS[tid] = c - c_lo; }  // 0 or 1
  }
  for (int p = tid; p < 400; p += 512) {
    int c0 = c_lo, c1 = c_lo + 1;
    f0s[p] = (c0 >= 128 && c0 < 256) ? feat[(b * 400 + p) * 128 + (c0 - 128)] : 0.f;
    f1s[p] = (c1 >= 128 && c1 < 256) ? feat[(b * 400 + p) * 128 + (c1 - 128)] : 0.f;
    scoreS[p] = 0.f;
  }

  // prefetch weight chunk 0 early (wbuf independent of everything above)
  {
    const char* g = (const char*)Apack + wid * 2048 + lane * 16;
    char* l = (char*)wbuf + wid * 2048;
    stage16(g, l); stage16(g + 1024, l + 1024);
  }
  __syncthreads();

  // ---- conv1 low-rank coefficients (parallel over all 512 threads)
  {
    int o = tid & 127, part = tid >> 7;
    const float* wr = wr1 + o * 256 + part * 64;
    float a = 0.f, w0 = 0.f, w1v = 0.f;
#pragma unroll 8
    for (int k = 0; k < 64; ++k) {
      float w = wr[k]; int cp = part * 64 + k; int s = selS[cp];
      if (s < 0)       a   += w * fA[cp];
      else if (s == 0) w0  += w;
      else             w1v += w;
    }
    atomicAdd(&AvecS[o], a); atomicAdd(&wB0s[o], w0); atomicAdd(&wB1s[o], w1v);
  }
  __syncthreads();

  // ---- phase 1: r1 = SiLU(BN(low-rank)) -> LDS bf16, fragment-major, b128 writes
  for (int idx = tid; idx < 6400; idx += 512) {         // 16 planes x 400 px
    int plane = idx / 400, p = idx - plane * 400;
    int c0 = (plane >> 2) * 32 + (plane & 3) * 8;
    float fa0 = f0s[p], fa1 = f1s[p];
    unsigned int pk[4];
#pragma unroll
    for (int jp = 0; jp < 4; ++jp) {
      int c = c0 + jp * 2;
      float y0 = AvecS[c]     + wB0s[c]     * fa0 + wB1s[c]     * fa1;
      float y1 = AvecS[c + 1] + wB0s[c + 1] * fa0 + wB1s[c + 1] * fa1;
      y0 = y0 * sc1[c] + sh1[c];  y1 = y1 * sc1[c + 1] + sh1[c + 1];
      pk[jp] = (unsigned int)f2bf(silu(y0)) | ((unsigned int)f2bf(silu(y1)) << 16);
    }
    *(uint4*)&r1f[(plane * 401 + p) * 8] = make_uint4(pk[0], pk[1], pk[2], pk[3]);
  }
  if (tid < 16) *(uint4*)&r1f[(tid * 401 + 400) * 8] = make_uint4(0, 0, 0, 0);  // zero pads

  // ---- phase 2: conv2 as 9 shifted GEMMs, MFMA 16x16x32 bf16, dbuf weight chunks
  int wm = wid & 1, wn = wid >> 1;           // 2 m-halves x 4 n-groups
  int ntcnt = (wn == 0) ? 7 : 6;             // tiles: wn + 4*t  (25 tiles -> 7/6/6/6)
  int n16 = lane & 15, quad = lane >> 4;

  int hA[7], wA[7];
#pragma unroll
  for (int t = 0; t < 7; ++t) {
    int p = (wn + 4 * t) * 16 + n16;
    hA[t] = p / 20; wA[t] = p - 20 * hA[t];
  }

  f32x4 acc[4][7];
#pragma unroll
  for (int mt = 0; mt < 4; ++mt)
#pragma unroll
    for (int t = 0; t < 7; ++t) acc[mt][t] = f32x4{0.f, 0.f, 0.f, 0.f};

  __syncthreads();   // r1f writes visible; chunk 0 staged (vmcnt drained by barrier)

  for (int cc = 0; cc < 18; ++cc) {
    if (cc < 17) {   // prefetch next chunk into the other buffer
      const char* g = (const char*)Apack + (size_t)(cc + 1) * 16384 + wid * 2048 + lane * 16;
      char* l = (char*)wbuf + ((cc + 1) & 1) * 16384 + wid * 2048;
      stage16(g, l); stage16(g + 1024, l + 1024);
    }
    int tap = cc >> 1, khalf = cc & 1;
    int dy = tap / 3 - 1, dx = tap % 3 - 1;
    const unsigned short* wb = wbuf + (cc & 1) * 8192;

    int pp[7];
#pragma unroll
    for (int t = 0; t < 7; ++t) {
      if (t < ntcnt) {
        int hh = hA[t] + dy, ww = wA[t] + dx;
        bool valid = (hh >= 0) & (hh < 20) & (ww >= 0) & (ww < 20);
        pp[t] = valid ? hh * 20 + ww : 400;
      }
    }
#pragma unroll
    for (int ksl = 0; ksl < 2; ++ksl) {
      int ks = khalf * 2 + ksl;
      bf16x8 afr[4];
#pragma unroll
      for (int mt = 0; mt < 4; ++mt)
        afr[mt] = *(const bf16x8*)&wb[((ksl * 8 + wm * 4 + mt) * 64 + lane) * 8];
      int pbase = (ks * 4 + quad) * 401;
#pragma unroll
      for (int t = 0; t < 7; ++t) {
        if (t < ntcnt) {                       // wave-uniform predicate
          bf16x8 bfr = *(const bf16x8*)&r1f[(pbase + pp[t]) * 8];
          acc[0][t] = __builtin_amdgcn_mfma_f32_16x16x32_bf16(afr[0], bfr, acc[0][t], 0, 0, 0);
          acc[1][t] = __builtin_amdgcn_mfma_f32_16x16x32_bf16(afr[1], bfr, acc[1][t], 0, 0, 0);
          acc[2][t] = __builtin_amdgcn_mfma_f32_16x16x32_bf16(afr[2], bfr, acc[2][t], 0, 0, 0);
          acc[3][t] = __builtin_amdgcn_mfma_f32_16x16x32_bf16(afr[3], bfr, acc[3][t], 0, 0, 0);
        }
      }
    }
    __syncthreads();   // readers done with buf[cc&1]; prefetch cc+1 landed everywhere
  }

  // ---- epilogue: BN2+SiLU, conv3 (dot w3c), reduce to scoreS[p]
#pragma unroll
  for (int t = 0; t < 7; ++t) {
    if (t < ntcnt) {
      float ps = 0.f;
#pragma unroll
      for (int mt = 0; mt < 4; ++mt) {
#pragma unroll
        for (int r = 0; r < 4; ++r) {
          int o = wm * 64 + mt * 16 + quad * 4 + r;
          float y = acc[mt][t][r] * sc2[o] + sh2[o];
          ps += silu(y) * w3c[o];
        }
      }
      ps += __shfl_xor(ps, 16);
      ps += __shfl_xor(ps, 32);
      if (quad == 0) atomicAdd(&scoreS[(wn + 4 * t) * 16 + n16], ps);
    }
  }
  __syncthreads();

  // ---- BN3 + SiLU on scores
  float s3 = gr3[0] * rsqrtf(vr3[0] + EPS);
  float sh3v = br3[0] - mr3[0] * s3;
  for (int p = tid; p < 400; p += 512)
    scoreS[p] = silu(scoreS[p] * s3 + sh3v);
  __syncthreads();

  // ---- att row: att[b,q,c] = sum_j score[j] * feat[b,j,c]
  {
    int c = tid & 127, part = tid >> 7;
    float s = 0.f;
    int j0 = part * 100;
    for (int j = j0; j < j0 + 100; ++j)
      s += scoreS[j] * feat[(b * 400 + j) * 128 + c];
    atomicAdd(&attT[c], s);
  }
  __syncthreads();
  if (tid < 128)
    att[((size_t)(b * 400 + q)) * 128 + tid] = attT[tid];
}

// ---------------- out = SiLU(BN(conv1x1(att, w2))) + x
__global__ void out_kernel(const float* __restrict__ att, const float* __restrict__ x,
                           const float* __restrict__ w2,
                           const float* __restrict__ g2, const float* __restrict__ b2,
                           const float* __restrict__ m2, const float* __restrict__ v2,
                           float* __restrict__ out) {
  int blk = blockIdx.x; int b = blk / 400, p = blk % 400;
  int tid = threadIdx.x;
  __shared__ float av[128];
  av[tid] = att[(size_t)(b * 400 + p) * 128 + tid];
  __syncthreads();
  const float* wrow = w2 + tid * 128;
  float s = 0.f;
#pragma unroll 8
  for (int ci = 0; ci < 128; ++ci) s += wrow[ci] * av[ci];
  float sc = g2[tid] * rsqrtf(v2[tid] + EPS);
  float y = s * sc + (b2[tid] - m2[tid] * sc);
  int xi = (b * 128 + tid) * 400 + p;
  out[xi] = silu(y) + x[xi];
}

extern "C" void kernel_launch(void* const* d_in, const int* in_sizes, int n_in,
                              void* d_out, int out_size, void* d_ws, size_t ws_size,
                              hipStream_t stream) {
  const float* x   = (const float*)d_in[0];
  const float* w1  = (const float*)d_in[1];
  const float* g1  = (const float*)d_in[2];
  const float* b1  = (const float*)d_in[3];
  const float* m1  = (const float*)d_in[4];
  const float* v1  = (const float*)d_in[5];
  const float* w2  = (const float*)d_in[6];
  const float* g2  = (const float*)d_in[7];
  const float* b2  = (const float*)d_in[8];
  const float* m2  = (const float*)d_in[9];
  const float* v2  = (const float*)d_in[10];
  const float* wr1 = (const float*)d_in[11];
  const float* gr1 = (const float*)d_in[12];
  const float* br1 = (const float*)d_in[13];
  const float* mr1 = (const float*)d_in[14];
  const float* vr1 = (const float*)d_in[15];
  const float* wr2 = (const float*)d_in[16];
  const float* gr2 = (const float*)d_in[17];
  const float* br2 = (const float*)d_in[18];
  const float* mr2 = (const float*)d_in[19];
  const float* vr2 = (const float*)d_in[20];
  const float* wr3 = (const float*)d_in[21];
  const float* gr3 = (const float*)d_in[22];
  const float* br3 = (const float*)d_in[23];
  const float* mr3 = (const float*)d_in[24];
  const float* vr3 = (const float*)d_in[25];
  float* out = (float*)d_out;

  char* ws = (char*)d_ws;
  float* feat = (float*)ws;                                // 409600 B
  float* attb = (float*)(ws + 409600);                     // 409600 B
  unsigned short* Apack = (unsigned short*)(ws + 819200);  // 294912 B

  prep_kernel<<<944, 128, 0, stream>>>(x, w1, g1, b1, m1, v1, wr2, feat, Apack);
  rel_kernel<<<800, 512, 0, stream>>>(feat, wr1, gr1, br1, mr1, vr1, Apack,
                                      gr2, br2, mr2, vr2, wr3, gr3, br3, mr3, vr3, attb);
  out_kernel<<<800, 128, 0, stream>>>(attb, x, w2, g2, b2, m2, v2, out);
}